// Round 1
// baseline (396.781 us; speedup 1.0000x reference)
//
#include <hip/hip_runtime.h>
#include <math.h>

#define N   8192
#define NZ  256
#define NC  128
#define DT  0.1f

__device__ __forceinline__ float wave_reduce(float v) {
    #pragma unroll
    for (int off = 32; off > 0; off >>= 1)
        v += __shfl_down(v, off, 64);
    return v;
}

__device__ __forceinline__ float dot4(float4 a, float4 b) {
    return a.x * b.x + a.y * b.y + a.z * b.z + a.w * b.w;
}

// K1: r = tanh(x + b)
__global__ void k1_r(const float* __restrict__ x, const float* __restrict__ b,
                     float* __restrict__ r) {
    int i = blockIdx.x * blockDim.x + threadIdx.x;
    if (i < N) r[i] = tanhf(x[i] + b[i]);
}

// K2: z = W_rz @ r  (NZ rows x N cols, row-major). One wave per row.
__global__ void k2_z(const float* __restrict__ Wrz, const float* __restrict__ r,
                     float* __restrict__ z) {
    int wave = (blockIdx.x * blockDim.x + threadIdx.x) >> 6;
    int lane = threadIdx.x & 63;
    if (wave >= NZ) return;
    const float4* row = (const float4*)(Wrz + (size_t)wave * N);
    const float4* r4  = (const float4*)r;
    float acc = 0.f;
    #pragma unroll
    for (int k = 0; k < N / 4 / 64; ++k) {
        int idx = lane + k * 64;
        acc += dot4(row[idx], r4[idx]);
    }
    acc = wave_reduce(acc);
    if (lane == 0) z[wave] = acc;
}

// K3: dx_i = dot(W_rr[i],r) + dot(W_epsr[i],eps) + dot(W_zr[i],z) + dot(W_cr[i],c) - x_i
//     x_new = x + DT*dx ; r_new = tanh(x_new + b). One wave per row.
__global__ void k3_main(const float* __restrict__ Wrr,
                        const float* __restrict__ Wepsr,
                        const float* __restrict__ Wzr,
                        const float* __restrict__ Wcr,
                        const float* __restrict__ r,
                        const float* __restrict__ eps,
                        const float* __restrict__ z,
                        const float* __restrict__ c,
                        const float* __restrict__ x,
                        const float* __restrict__ b,
                        float* __restrict__ out) {
    int row  = (blockIdx.x * blockDim.x + threadIdx.x) >> 6;
    int lane = threadIdx.x & 63;
    if (row >= N) return;

    const float4* wr = (const float4*)(Wrr + (size_t)row * N);
    const float4* r4 = (const float4*)r;
    float acc = 0.f;
    #pragma unroll
    for (int k = 0; k < N / 4 / 64; ++k) {   // 32 iters of float4
        int idx = lane + k * 64;
        acc += dot4(wr[idx], r4[idx]);
    }
    // W_epsr[row] (256) . eps : 64 lanes x float4
    {
        const float4* we = (const float4*)(Wepsr + (size_t)row * NZ);
        const float4* e4 = (const float4*)eps;
        acc += dot4(we[lane], e4[lane]);
    }
    // W_zr[row] (256) . z
    {
        const float4* wz = (const float4*)(Wzr + (size_t)row * NZ);
        const float4* z4 = (const float4*)z;
        acc += dot4(wz[lane], z4[lane]);
    }
    // W_cr[row] (128) . c : lanes 0..31
    if (lane < NC / 4) {
        const float4* wc = (const float4*)(Wcr + (size_t)row * NC);
        const float4* c4 = (const float4*)c;
        acc += dot4(wc[lane], c4[lane]);
    }
    acc = wave_reduce(acc);
    if (lane == 0) {
        float xi = x[row];
        float dx = acc - xi;
        float xn = xi + DT * dx;
        float rn = tanhf(xn + b[row]);
        out[row]     = xn;   // x_new
        out[N + row] = rn;   // r_new
    }
}

// K4: z_new = W_rz @ r_new ; c_new = W_rc @ r_new ; eps_new = z_new - z_tilde
// One wave per output row (NZ + NC = 384 waves).
__global__ void k4_heads(const float* __restrict__ Wrz,
                         const float* __restrict__ Wrc,
                         const float* __restrict__ rnew,
                         const float* __restrict__ ztilde,
                         float* __restrict__ out) {
    int wave = (blockIdx.x * blockDim.x + threadIdx.x) >> 6;
    int lane = threadIdx.x & 63;
    if (wave >= NZ + NC) return;
    const float* Wrow = (wave < NZ) ? (Wrz + (size_t)wave * N)
                                    : (Wrc + (size_t)(wave - NZ) * N);
    const float4* w4 = (const float4*)Wrow;
    const float4* r4 = (const float4*)rnew;
    float acc = 0.f;
    #pragma unroll
    for (int k = 0; k < N / 4 / 64; ++k) {
        int idx = lane + k * 64;
        acc += dot4(w4[idx], r4[idx]);
    }
    acc = wave_reduce(acc);
    if (lane == 0) {
        if (wave < NZ) {
            out[2 * N + wave]           = acc;                  // z_new
            out[2 * N + NZ + NC + wave] = acc - ztilde[wave];   // eps_new
        } else {
            out[2 * N + NZ + (wave - NZ)] = acc;                // c_new
        }
    }
}

extern "C" void kernel_launch(void* const* d_in, const int* in_sizes, int n_in,
                              void* d_out, int out_size, void* d_ws, size_t ws_size,
                              hipStream_t stream) {
    const float* x      = (const float*)d_in[0];
    const float* eps    = (const float*)d_in[1];
    const float* c      = (const float*)d_in[2];
    const float* ztilde = (const float*)d_in[3];
    const float* Wrr    = (const float*)d_in[4];
    const float* Wzr    = (const float*)d_in[5];
    const float* Wcr    = (const float*)d_in[6];
    const float* Wepsr  = (const float*)d_in[7];
    const float* Wrz    = (const float*)d_in[8];
    const float* Wrc    = (const float*)d_in[9];
    const float* b      = (const float*)d_in[10];
    float* out = (float*)d_out;

    float* r = (float*)d_ws;        // N floats
    float* z = r + N;               // NZ floats

    k1_r<<<N / 256, 256, 0, stream>>>(x, b, r);
    k2_z<<<(NZ * 64) / 256, 256, 0, stream>>>(Wrz, r, z);
    k3_main<<<(N * 64) / 256, 256, 0, stream>>>(Wrr, Wepsr, Wzr, Wcr,
                                                r, eps, z, c, x, b, out);
    k4_heads<<<((NZ + NC) * 64) / 256, 256, 0, stream>>>(Wrz, Wrc, out + N,
                                                         ztilde, out);
}